// Round 11
// baseline (63.966 us; speedup 1.0000x reference)
//
#include <hip/hip_runtime.h>
#include <hip/hip_bf16.h>
#include <float.h>
#include <math.h>

#define BB 64
#define T1 33
#define TT 32
#define II 197
#define CC 512
#define TEMP 0.07f

typedef float f32x4 __attribute__((ext_vector_type(4)));
typedef int i32x4 __attribute__((ext_vector_type(4)));
typedef int i32x8 __attribute__((ext_vector_type(8)));

// ---- workspace layout (bytes) ----
// Frag records for mfma_scale_f32_16x16x128_f8f6f4 (fp8): per frag per kstep,
// 2048 B = [half h 0..1][lane 0..63][16 B]; element (row/col = lane&15,
// k = ks*128 + (lane>>4)*32 + h*16 + j).
// tl8: [xc8 8][ks 4][fa 16] records  (1 MB)   A: text rows r=fa*16+(lane&15)
// ve8: [y 64][ks 4][fb 16] records  (8 MB)   B: cols  i=fb*16+(lane&15); fb<=12 written
// tti: [64 x][64 y] f32
#define TL_OFF  0
#define VE_OFF  (1 << 20)                  // 1 MB
#define TTI_OFF ((1 << 20) + (8 << 20))    // 9 MB
#define KS_STRIDE   32768                  // 16 frags * 2048
#define GRP_STRIDE  131072                 // 4 ks * KS_STRIDE

// grid (64, 8): hz 0..3 = video c-chunks (= ksteps), hz 4..7 = text c-chunks.
// 512 threads. Pass 1 caches the block's 100 KB row-chunk in LDS; pass 2
// builds fp8 records from LDS (inputs read from HBM exactly once, coalesced).
__global__ __launch_bounds__(512) void norm_all_kernel(const float* __restrict__ text,
                                                       const float* __restrict__ video,
                                                       unsigned char* __restrict__ tl8,
                                                       unsigned char* __restrict__ ve8) {
  int b = blockIdx.x, hz = blockIdx.y, tid = threadIdx.x;
  bool isV = hz < 4;
  int h2 = isV ? hz : hz - 4;                  // kstep
  const float* src = isV ? (video + (size_t)b * II * CC) : (text + (size_t)b * T1 * CC);
  int n = isV ? II : T1;

  __shared__ float cache[II][132];   // 104 KB: rows x 128-float chunk (pad 4)
  __shared__ float red[16][128];     // 8 KB
  __shared__ float rn[128];

  // pass 1: coalesced chunk read -> LDS cache + sum of squares over rows
  {
    int c4 = tid & 31, rg = tid >> 5;          // rg 0..15
    const float* p = src + h2 * 128 + c4 * 4;
    float4 s = {0.f, 0.f, 0.f, 0.f};
    for (int i = rg; i < n; i += 16) {
      float4 v = *(const float4*)(p + (size_t)i * CC);
      *(float4*)&cache[i][c4 * 4] = v;
      s.x += v.x * v.x; s.y += v.y * v.y; s.z += v.z * v.z; s.w += v.w * v.w;
    }
    *(float4*)&red[rg][c4 * 4] = s;
  }
  __syncthreads();
  if (tid < 128) {
    float s = 0.f;
#pragma unroll
    for (int g = 0; g < 16; ++g) s += red[g][tid];
    rn[tid] = 1.0f / sqrtf(s);
  }
  __syncthreads();

  // pass 2: build 16-B record slices from the LDS cache, fp8 e4m3.
  // slice (frag f, half h, lane l): row/col = f*16+(l&15),
  // chunk-local channels = (l>>4)*32 + h*16 + {0..15}
  if (isV) {
    for (int S = tid; S < 13 * 128; S += 512) {
      int fb = S >> 7, h = (S >> 6) & 1, lane = S & 63;
      int i = fb * 16 + (lane & 15);
      int kloc = ((lane >> 4) & 3) * 32 + h * 16;
      unsigned int wd[4];
#pragma unroll
      for (int q = 0; q < 4; ++q) {
        f32x4 u = {0.f, 0.f, 0.f, 0.f};
        if (i < II) u = *(const f32x4*)&cache[i][kloc + q * 4];
        f32x4 r = *(const f32x4*)&rn[kloc + q * 4];
        int wv = __builtin_amdgcn_cvt_pk_fp8_f32(u[0] * r[0], u[1] * r[1], 0, 0);
        wv = __builtin_amdgcn_cvt_pk_fp8_f32(u[2] * r[2], u[3] * r[3], wv, 1);
        wd[q] = (unsigned int)wv;
      }
      unsigned char* dst = ve8 + (size_t)b * GRP_STRIDE + h2 * KS_STRIDE +
                           fb * 2048 + h * 1024 + lane * 16;
      *(uint4*)dst = make_uint4(wd[0], wd[1], wd[2], wd[3]);
    }
  } else if (tid < 256) {
    // 2 fa_local x 2 h x 64 lane = 256 slices
    int fa_local = tid >> 7, h = (tid >> 6) & 1, lane = tid & 63;
    int t = fa_local * 16 + (lane & 15);          // 0..31
    int kloc = ((lane >> 4) & 3) * 32 + h * 16;
    unsigned int wd[4];
#pragma unroll
    for (int q = 0; q < 4; ++q) {
      f32x4 u = *(const f32x4*)&cache[1 + t][kloc + q * 4];
      f32x4 r = *(const f32x4*)&rn[kloc + q * 4];
      int wv = __builtin_amdgcn_cvt_pk_fp8_f32(u[0] * r[0], u[1] * r[1], 0, 0);
      wv = __builtin_amdgcn_cvt_pk_fp8_f32(u[2] * r[2], u[3] * r[3], wv, 1);
      wd[q] = (unsigned int)wv;
    }
    int fa = (b & 7) * 2 + fa_local;
    unsigned char* dst = tl8 + (size_t)(b >> 3) * GRP_STRIDE + h2 * KS_STRIDE +
                         fa * 2048 + h * 1024 + lane * 16;
    *(uint4*)dst = make_uint4(wd[0], wd[1], wd[2], wd[3]);
  }
}

// ROUND-9 sim (best config, verbatim): zero-LDS direct-to-register.
// 2048 blocks x 512 threads, 64 rows x 208 cols, 4 ksteps of 128
// (mfma_scale 16x16x128 fp8, scales=1.0), #pragma unroll 1.
// ROUND-11 DIAGNOSTIC: this kernel is launched TWICE (idempotent: reads
// tl8/ve8/mask only, writes the same tti values). dur delta vs round 9's
// 41.87 us measures sim's true duration, which the top-5 counter filter
// has hidden since round 2. L2-BW theory predicts sim ~20-22 us (720 MB
// through L2 at 34.5 TB/s); if the delta is ~13-15 us instead, the
// remaining time is in norm/loss/launch gaps and the plan pivots.
__global__ __launch_bounds__(512, 4) void sim_kernel(const unsigned char* __restrict__ tl8,
                                                     const unsigned char* __restrict__ ve8,
                                                     const int* __restrict__ mask,
                                                     float* __restrict__ tti) {
  int L = blockIdx.x;
  int xcd = L & 7;
  int idx = L >> 3;              // 0..255
  int y = xcd * 8 + (idx & 7);   // each XCD owns 8 consecutive y's
  int xcb = idx >> 3;            // 0..31 : 2 batch-x per block (64 rows)

  int tid = threadIdx.x;
  int w = tid >> 6, lane = tid & 63;
  int wm = w & 1;                // rows wm*32..+32 (2 frags)
  int wn = w >> 1;               // col frags wn, wn+4, wn+8 (+12 if wn==0)

  __shared__ float smax[4 * 64]; // [wn][row] 1 KB

  const unsigned char* Abase =
      tl8 + (size_t)(xcb >> 2) * GRP_STRIDE + (size_t)(xcb & 3) * 4 * 2048;
  const unsigned char* Bbase = ve8 + (size_t)y * GRP_STRIDE;

  f32x4 acc[2][4] = {};

#pragma unroll 1
  for (int s = 0; s < 4; ++s) {
    const unsigned char* ab = Abase + (size_t)s * KS_STRIDE + lane * 16;
    const unsigned char* bb = Bbase + (size_t)s * KS_STRIDE + lane * 16;

    i32x8 aop[2];
#pragma unroll
    for (int ma = 0; ma < 2; ++ma) {
      const unsigned char* p = ab + (wm * 2 + ma) * 2048;
      i32x4 h0 = *(const i32x4*)p;
      i32x4 h1 = *(const i32x4*)(p + 1024);
      aop[ma] = __builtin_shufflevector(h0, h1, 0, 1, 2, 3, 4, 5, 6, 7);
    }

#pragma unroll
    for (int nb = 0; nb < 3; ++nb) {
      int fb = wn + 4 * nb;
      const unsigned char* p = bb + fb * 2048;
      i32x4 h0 = *(const i32x4*)p;
      i32x4 h1 = *(const i32x4*)(p + 1024);
      i32x8 bop = __builtin_shufflevector(h0, h1, 0, 1, 2, 3, 4, 5, 6, 7);
#pragma unroll
      for (int ma = 0; ma < 2; ++ma)
        acc[ma][nb] = __builtin_amdgcn_mfma_scale_f32_16x16x128_f8f6f4(
            aop[ma], bop, acc[ma][nb], 0, 0,
            0, 0x7F7F7F7F, 0, 0x7F7F7F7F);
    }
    if (wn == 0) {
      const unsigned char* p = bb + 12 * 2048;
      i32x4 h0 = *(const i32x4*)p;
      i32x4 h1 = *(const i32x4*)(p + 1024);
      i32x8 bop = __builtin_shufflevector(h0, h1, 0, 1, 2, 3, 4, 5, 6, 7);
#pragma unroll
      for (int ma = 0; ma < 2; ++ma)
        acc[ma][3] = __builtin_amdgcn_mfma_scale_f32_16x16x128_f8f6f4(
            aop[ma], bop, acc[ma][3], 0, 0,
            0, 0x7F7F7F7F, 0, 0x7F7F7F7F);
    }
  }

  // ---- fused epilogue: max over i (i<197), masked mean over t -> tti ----
  int col = lane & 15, gq = lane >> 4;
  int nfrag = (wn == 0) ? 4 : 3;
  bool valid[4];
#pragma unroll
  for (int nb = 0; nb < 4; ++nb) {
    int fb = wn + 4 * nb;
    valid[nb] = (nb < nfrag) && (fb * 16 + col < II);
  }

  float mx[2][4];
#pragma unroll
  for (int ma = 0; ma < 2; ++ma)
#pragma unroll
    for (int reg = 0; reg < 4; ++reg) {
      float m = -FLT_MAX;
#pragma unroll
      for (int nb = 0; nb < 4; ++nb)
        if (valid[nb]) m = fmaxf(m, acc[ma][nb][reg]);
      mx[ma][reg] = m;
    }
#pragma unroll
  for (int st = 1; st <= 8; st <<= 1)
#pragma unroll
    for (int ma = 0; ma < 2; ++ma)
#pragma unroll
      for (int reg = 0; reg < 4; ++reg)
        mx[ma][reg] = fmaxf(mx[ma][reg], __shfl_xor(mx[ma][reg], st));

  if (col == 0) {
#pragma unroll
    for (int ma = 0; ma < 2; ++ma)
#pragma unroll
      for (int reg = 0; reg < 4; ++reg)
        smax[wn * 64 + wm * 32 + ma * 16 + gq * 4 + reg] = mx[ma][reg];
  }
  __syncthreads();

  if (tid < 64) {
    int r = tid;                       // row = x_local*32 + t (x_local 0..1)
    float m = fmaxf(fmaxf(smax[r], smax[64 + r]),
                    fmaxf(smax[128 + r], smax[192 + r]));
    int x = xcb * 2 + (r >> 5), tt = r & 31;
    int mk = mask[x * T1 + 1 + tt];
    float num = mk ? m * TEMP : 0.f;
    float cnt = mk ? 1.f : 0.f;
#pragma unroll
    for (int st = 1; st < 32; st <<= 1) {
      num += __shfl_xor(num, st);
      cnt += __shfl_xor(cnt, st);
    }
    if (tt == 0) tti[x * 64 + y] = num / fmaxf(cnt, 1e-6f);
  }
}

// 1 block x 1024 threads: 16 threads per row x, each sums 4 y's.
__global__ void loss_kernel(const float* __restrict__ tti, float* __restrict__ out) {
  __shared__ float lxs[64];
  int tid = threadIdx.x;
  int x = tid >> 4, q = tid & 15;
  float4 v = *(const float4*)&tti[x * 64 + q * 4];
  float den = expf(v.x) + expf(v.y) + expf(v.z) + expf(v.w);
#pragma unroll
  for (int st = 1; st < 16; st <<= 1) den += __shfl_xor(den, st);
  if (q == 0) {
    float pos = expf(tti[x * 64 + x]);
    lxs[x] = -logf(pos / den + 1e-20f);
  }
  __syncthreads();
  if (tid < 64) {
    float lx = lxs[tid];
#pragma unroll
    for (int s = 1; s < 64; s <<= 1) lx += __shfl_xor(lx, s);
    if (tid == 0) out[0] = lx * (1.0f / 64.0f);
  }
}

extern "C" void kernel_launch(void* const* d_in, const int* in_sizes, int n_in,
                              void* d_out, int out_size, void* d_ws, size_t ws_size,
                              hipStream_t stream) {
  const float* text = (const float*)d_in[0];   // [64][33][512] f32
  const float* video = (const float*)d_in[1];  // [64][197][512] f32
  const int* mask = (const int*)d_in[2];       // [64][33] i32
  float* out = (float*)d_out;

  char* ws = (char*)d_ws;
  unsigned char* tl8 = (unsigned char*)(ws + TL_OFF);
  unsigned char* ve8 = (unsigned char*)(ws + VE_OFF);
  float* tti = (float*)(ws + TTI_OFF);

  hipLaunchKernelGGL(norm_all_kernel, dim3(BB, 8), dim3(512), 0, stream, text, video, tl8, ve8);
  // DIAGNOSTIC: sim launched twice (idempotent). dur - 41.9us = sim duration.
  hipLaunchKernelGGL(sim_kernel, dim3(2048), dim3(512), 0, stream, tl8, ve8, mask, tti);
  hipLaunchKernelGGL(sim_kernel, dim3(2048), dim3(512), 0, stream, tl8, ve8, mask, tti);
  hipLaunchKernelGGL(loss_kernel, dim3(1), dim3(1024), 0, stream, tti, out);
}

// Round 12
// 44.173 us; speedup vs baseline: 1.4481x; 1.4481x over previous
//
#include <hip/hip_runtime.h>
#include <hip/hip_bf16.h>
#include <float.h>
#include <math.h>

#define BB 64
#define T1 33
#define TT 32
#define II 197
#define CC 512
#define TEMP 0.07f

typedef float f32x4 __attribute__((ext_vector_type(4)));
typedef int i32x4 __attribute__((ext_vector_type(4)));
typedef int i32x8 __attribute__((ext_vector_type(8)));

// ---- workspace layout (bytes) ----
// Frag records for mfma_scale_f32_16x16x128_f8f6f4 (fp8): per frag per kstep,
// 2048 B = [half h 0..1][lane 0..63][16 B]; element (row/col = lane&15,
// k = ks*128 + (lane>>4)*32 + h*16 + j).
// tl8: [xc8 8][ks 4][fa 16] records  (1 MB)   A: text rows r=fa*16+(lane&15)
// ve8: [y 64][ks 4][fb 16] records  (8 MB)   B: cols  i=fb*16+(lane&15); fb<=12 written
// tti: [64 x][64 y] f32
#define TL_OFF  0
#define VE_OFF  (1 << 20)                  // 1 MB
#define TTI_OFF ((1 << 20) + (8 << 20))    // 9 MB
#define KS_STRIDE   32768                  // 16 frags * 2048
#define GRP_STRIDE  131072                 // 4 ks * KS_STRIDE

// grid (64, 8): hz 0..3 = video c-chunks (= ksteps), hz 4..7 = text c-chunks.
// 512 threads. Pass 1 caches the block's 100 KB row-chunk in LDS; pass 2
// builds fp8 records from LDS (inputs read from HBM exactly once, coalesced).
__global__ __launch_bounds__(512) void norm_all_kernel(const float* __restrict__ text,
                                                       const float* __restrict__ video,
                                                       unsigned char* __restrict__ tl8,
                                                       unsigned char* __restrict__ ve8) {
  int b = blockIdx.x, hz = blockIdx.y, tid = threadIdx.x;
  bool isV = hz < 4;
  int h2 = isV ? hz : hz - 4;                  // kstep
  const float* src = isV ? (video + (size_t)b * II * CC) : (text + (size_t)b * T1 * CC);
  int n = isV ? II : T1;

  __shared__ float cache[II][132];   // 104 KB: rows x 128-float chunk (pad 4)
  __shared__ float red[16][128];     // 8 KB
  __shared__ float rn[128];

  // pass 1: coalesced chunk read -> LDS cache + sum of squares over rows
  {
    int c4 = tid & 31, rg = tid >> 5;          // rg 0..15
    const float* p = src + h2 * 128 + c4 * 4;
    float4 s = {0.f, 0.f, 0.f, 0.f};
    for (int i = rg; i < n; i += 16) {
      float4 v = *(const float4*)(p + (size_t)i * CC);
      *(float4*)&cache[i][c4 * 4] = v;
      s.x += v.x * v.x; s.y += v.y * v.y; s.z += v.z * v.z; s.w += v.w * v.w;
    }
    *(float4*)&red[rg][c4 * 4] = s;
  }
  __syncthreads();
  if (tid < 128) {
    float s = 0.f;
#pragma unroll
    for (int g = 0; g < 16; ++g) s += red[g][tid];
    rn[tid] = 1.0f / sqrtf(s);
  }
  __syncthreads();

  // pass 2: build 16-B record slices from the LDS cache, fp8 e4m3.
  // slice (frag f, half h, lane l): row/col = f*16+(l&15),
  // chunk-local channels = (l>>4)*32 + h*16 + {0..15}
  if (isV) {
    for (int S = tid; S < 13 * 128; S += 512) {
      int fb = S >> 7, h = (S >> 6) & 1, lane = S & 63;
      int i = fb * 16 + (lane & 15);
      int kloc = ((lane >> 4) & 3) * 32 + h * 16;
      unsigned int wd[4];
#pragma unroll
      for (int q = 0; q < 4; ++q) {
        f32x4 u = {0.f, 0.f, 0.f, 0.f};
        if (i < II) u = *(const f32x4*)&cache[i][kloc + q * 4];
        f32x4 r = *(const f32x4*)&rn[kloc + q * 4];
        int wv = __builtin_amdgcn_cvt_pk_fp8_f32(u[0] * r[0], u[1] * r[1], 0, 0);
        wv = __builtin_amdgcn_cvt_pk_fp8_f32(u[2] * r[2], u[3] * r[3], wv, 1);
        wd[q] = (unsigned int)wv;
      }
      unsigned char* dst = ve8 + (size_t)b * GRP_STRIDE + h2 * KS_STRIDE +
                           fb * 2048 + h * 1024 + lane * 16;
      *(uint4*)dst = make_uint4(wd[0], wd[1], wd[2], wd[3]);
    }
  } else if (tid < 256) {
    // 2 fa_local x 2 h x 64 lane = 256 slices
    int fa_local = tid >> 7, h = (tid >> 6) & 1, lane = tid & 63;
    int t = fa_local * 16 + (lane & 15);          // 0..31
    int kloc = ((lane >> 4) & 3) * 32 + h * 16;
    unsigned int wd[4];
#pragma unroll
    for (int q = 0; q < 4; ++q) {
      f32x4 u = *(const f32x4*)&cache[1 + t][kloc + q * 4];
      f32x4 r = *(const f32x4*)&rn[kloc + q * 4];
      int wv = __builtin_amdgcn_cvt_pk_fp8_f32(u[0] * r[0], u[1] * r[1], 0, 0);
      wv = __builtin_amdgcn_cvt_pk_fp8_f32(u[2] * r[2], u[3] * r[3], wv, 1);
      wd[q] = (unsigned int)wv;
    }
    int fa = (b & 7) * 2 + fa_local;
    unsigned char* dst = tl8 + (size_t)(b >> 3) * GRP_STRIDE + h2 * KS_STRIDE +
                         fa * 2048 + h * 1024 + lane * 16;
    *(uint4*)dst = make_uint4(wd[0], wd[1], wd[2], wd[3]);
  }
}

typedef __attribute__((address_space(3))) unsigned int lds_u32;
typedef __attribute__((address_space(1))) const unsigned int glb_u32;
__device__ __forceinline__ void gl16(const unsigned char* g, unsigned char* l) {
  __builtin_amdgcn_global_load_lds((glb_u32*)(const void*)g, (lds_u32*)(void*)l, 16, 0, 0);
}

// ROUND-12 sim: hybrid A-in-LDS / B-direct. 2048 blocks x 512 threads,
// 64 rows x 208 cols, 4 ksteps of 128 (mfma_scale 16x16x128 fp8, scales=1).
// Round-11 diagnostic measured sim ~= 22 us ~= the 690 MB of L2 fragment
// traffic from wave replication (A x4 waves, B x2 waves); L1 couldn't dedup
// because the per-kstep working set (A 8KB + B 26KB = 34KB) exceeds 32KB L1.
// Fix: stage A (the x4-replicated operand, only 8KB/kstep = 1 gl16/thread)
// into a 16 KB ring-2 LDS buffer; B stays direct-to-register -- its 26 KB
// now fits L1, so the x2 wm-replication becomes L1 hits. Predicted L2
// traffic 278 MB (~8 us) + MFMA 6 us. acc 32 + aop 16 + transient bop ~75
// regs: no spill at the (512,4) 128 cap. Per-phase vmcnt(0)+barrier drain
// hidden by the co-resident block (2 blocks/CU, 4 waves/SIMD).
__global__ __launch_bounds__(512, 4) void sim_kernel(const unsigned char* __restrict__ tl8,
                                                     const unsigned char* __restrict__ ve8,
                                                     const int* __restrict__ mask,
                                                     float* __restrict__ tti) {
  int L = blockIdx.x;
  int xcd = L & 7;
  int idx = L >> 3;              // 0..255
  int y = xcd * 8 + (idx & 7);   // each XCD owns 8 consecutive y's
  int xcb = idx >> 3;            // 0..31 : 2 batch-x per block (64 rows)

  int tid = threadIdx.x;
  int w = tid >> 6, lane = tid & 63;
  int wm = w & 1;                // rows wm*32..+32 (2 frags)
  int wn = w >> 1;               // col frags wn, wn+4, wn+8 (+12 if wn==0)

  __shared__ __attribute__((aligned(16))) unsigned char As[2][4 * 2048];  // 16 KB ring-2
  __shared__ float smax[4 * 64];                                          // 1 KB

  const unsigned char* Abase =
      tl8 + (size_t)(xcb >> 2) * GRP_STRIDE + (size_t)(xcb & 3) * 4 * 2048;
  const unsigned char* Bbase = ve8 + (size_t)y * GRP_STRIDE;

  // A per kstep = 4 frags x 2048 B = 8 KB contiguous: exactly 1 gl16/thread.
  // LDS dst = wave-uniform base + lane*16 (linear both sides).
#define STG_A(s_) do {                                                        \
    const unsigned char* src_ = Abase + (size_t)(s_) * KS_STRIDE + tid * 16;  \
    unsigned char* dst_ = &As[(s_) & 1][0] + w * 1024 + lane * 16;            \
    gl16(src_, dst_);                                                         \
  } while (0)

  f32x4 acc[2][4] = {};

  STG_A(0);
  asm volatile("s_waitcnt vmcnt(0)" ::: "memory");
  __builtin_amdgcn_s_barrier();

#pragma unroll
  for (int s = 0; s < 4; ++s) {
    if (s < 3) STG_A(s + 1);
    int slot = s & 1;

    i32x8 aop[2];
#pragma unroll
    for (int ma = 0; ma < 2; ++ma) {
      const unsigned char* p = &As[slot][(wm * 2 + ma) * 2048 + lane * 16];
      i32x4 h0 = *(const i32x4*)p;
      i32x4 h1 = *(const i32x4*)(p + 1024);
      aop[ma] = __builtin_shufflevector(h0, h1, 0, 1, 2, 3, 4, 5, 6, 7);
    }

    const unsigned char* bb = Bbase + (size_t)s * KS_STRIDE + lane * 16;
#pragma unroll
    for (int nb = 0; nb < 3; ++nb) {
      int fb = wn + 4 * nb;
      const unsigned char* p = bb + fb * 2048;
      i32x4 h0 = *(const i32x4*)p;
      i32x4 h1 = *(const i32x4*)(p + 1024);
      i32x8 bop = __builtin_shufflevector(h0, h1, 0, 1, 2, 3, 4, 5, 6, 7);
#pragma unroll
      for (int ma = 0; ma < 2; ++ma)
        acc[ma][nb] = __builtin_amdgcn_mfma_scale_f32_16x16x128_f8f6f4(
            aop[ma], bop, acc[ma][nb], 0, 0,
            0, 0x7F7F7F7F, 0, 0x7F7F7F7F);
    }
    if (wn == 0) {
      const unsigned char* p = bb + 12 * 2048;
      i32x4 h0 = *(const i32x4*)p;
      i32x4 h1 = *(const i32x4*)(p + 1024);
      i32x8 bop = __builtin_shufflevector(h0, h1, 0, 1, 2, 3, 4, 5, 6, 7);
#pragma unroll
      for (int ma = 0; ma < 2; ++ma)
        acc[ma][3] = __builtin_amdgcn_mfma_scale_f32_16x16x128_f8f6f4(
            aop[ma], bop, acc[ma][3], 0, 0,
            0, 0x7F7F7F7F, 0, 0x7F7F7F7F);
    }

    if (s < 3) {
      // drain this phase's STG_A (1 op/thread) before anyone reads the slot;
      // B loads are already consumed by the MFMAs above.
      asm volatile("s_waitcnt vmcnt(0)" ::: "memory");
      __builtin_amdgcn_s_barrier();
    }
  }
#undef STG_A

  // ---- fused epilogue: max over i (i<197), masked mean over t -> tti ----
  int col = lane & 15, gq = lane >> 4;
  int nfrag = (wn == 0) ? 4 : 3;
  bool valid[4];
#pragma unroll
  for (int nb = 0; nb < 4; ++nb) {
    int fb = wn + 4 * nb;
    valid[nb] = (nb < nfrag) && (fb * 16 + col < II);
  }

  float mx[2][4];
#pragma unroll
  for (int ma = 0; ma < 2; ++ma)
#pragma unroll
    for (int reg = 0; reg < 4; ++reg) {
      float m = -FLT_MAX;
#pragma unroll
      for (int nb = 0; nb < 4; ++nb)
        if (valid[nb]) m = fmaxf(m, acc[ma][nb][reg]);
      mx[ma][reg] = m;
    }
#pragma unroll
  for (int st = 1; st <= 8; st <<= 1)
#pragma unroll
    for (int ma = 0; ma < 2; ++ma)
#pragma unroll
      for (int reg = 0; reg < 4; ++reg)
        mx[ma][reg] = fmaxf(mx[ma][reg], __shfl_xor(mx[ma][reg], st));

  if (col == 0) {
#pragma unroll
    for (int ma = 0; ma < 2; ++ma)
#pragma unroll
      for (int reg = 0; reg < 4; ++reg)
        smax[wn * 64 + wm * 32 + ma * 16 + gq * 4 + reg] = mx[ma][reg];
  }
  __syncthreads();

  if (tid < 64) {
    int r = tid;                       // row = x_local*32 + t (x_local 0..1)
    float m = fmaxf(fmaxf(smax[r], smax[64 + r]),
                    fmaxf(smax[128 + r], smax[192 + r]));
    int x = xcb * 2 + (r >> 5), tt = r & 31;
    int mk = mask[x * T1 + 1 + tt];
    float num = mk ? m * TEMP : 0.f;
    float cnt = mk ? 1.f : 0.f;
#pragma unroll
    for (int st = 1; st < 32; st <<= 1) {
      num += __shfl_xor(num, st);
      cnt += __shfl_xor(cnt, st);
    }
    if (tt == 0) tti[x * 64 + y] = num / fmaxf(cnt, 1e-6f);
  }
}

// 1 block x 1024 threads: 16 threads per row x, each sums 4 y's.
__global__ void loss_kernel(const float* __restrict__ tti, float* __restrict__ out) {
  __shared__ float lxs[64];
  int tid = threadIdx.x;
  int x = tid >> 4, q = tid & 15;
  float4 v = *(const float4*)&tti[x * 64 + q * 4];
  float den = expf(v.x) + expf(v.y) + expf(v.z) + expf(v.w);
#pragma unroll
  for (int st = 1; st < 16; st <<= 1) den += __shfl_xor(den, st);
  if (q == 0) {
    float pos = expf(tti[x * 64 + x]);
    lxs[x] = -logf(pos / den + 1e-20f);
  }
  __syncthreads();
  if (tid < 64) {
    float lx = lxs[tid];
#pragma unroll
    for (int s = 1; s < 64; s <<= 1) lx += __shfl_xor(lx, s);
    if (tid == 0) out[0] = lx * (1.0f / 64.0f);
  }
}

extern "C" void kernel_launch(void* const* d_in, const int* in_sizes, int n_in,
                              void* d_out, int out_size, void* d_ws, size_t ws_size,
                              hipStream_t stream) {
  const float* text = (const float*)d_in[0];   // [64][33][512] f32
  const float* video = (const float*)d_in[1];  // [64][197][512] f32
  const int* mask = (const int*)d_in[2];       // [64][33] i32
  float* out = (float*)d_out;

  char* ws = (char*)d_ws;
  unsigned char* tl8 = (unsigned char*)(ws + TL_OFF);
  unsigned char* ve8 = (unsigned char*)(ws + VE_OFF);
  float* tti = (float*)(ws + TTI_OFF);

  hipLaunchKernelGGL(norm_all_kernel, dim3(BB, 8), dim3(512), 0, stream, text, video, tl8, ve8);
  hipLaunchKernelGGL(sim_kernel, dim3(2048), dim3(512), 0, stream, tl8, ve8, mask, tti);
  hipLaunchKernelGGL(loss_kernel, dim3(1), dim3(1024), 0, stream, tti, out);
}